// Round 1
// baseline (663.374 us; speedup 1.0000x reference)
//
#include <hip/hip_runtime.h>
#include <hip/hip_bf16.h>
#include <math.h>

#define T_STEPS 4096
#define VOCAB   32000
// VOCAB/4 = 8000 float4 per row

__device__ __forceinline__ void argmax_combine(float& bv, int& bi, float ov, int oi) {
    // strictly greater wins; on exact tie, smaller index wins (jnp.argmax first-occurrence)
    if (ov > bv || (ov == bv && oi < bi)) { bv = ov; bi = oi; }
}

__global__ __launch_bounds__(256) void ctc_argmax_kernel(const float* __restrict__ em,
                                                         int* __restrict__ idx_out) {
    const int t   = blockIdx.x;
    const int tid = threadIdx.x;
    const float4* row4 = (const float4*)(em + (size_t)t * VOCAB);

    float bv = -INFINITY;
    int   bi = 0x7fffffff;

    // Each thread walks ascending indices, so strict '>' preserves first-occurrence
    // semantics within the thread (3 VALU ops/element).
    for (int j = tid; j < VOCAB / 4; j += 256) {
        float4 v = row4[j];
        const int base = j * 4;
        if (v.x > bv) { bv = v.x; bi = base + 0; }
        if (v.y > bv) { bv = v.y; bi = base + 1; }
        if (v.z > bv) { bv = v.z; bi = base + 2; }
        if (v.w > bv) { bv = v.w; bi = base + 3; }
    }

    // wave (64-lane) reduction with tie handling
    #pragma unroll
    for (int off = 32; off > 0; off >>= 1) {
        float ov = __shfl_down(bv, off, 64);
        int   oi = __shfl_down(bi, off, 64);
        argmax_combine(bv, bi, ov, oi);
    }

    // block reduction across 4 waves
    __shared__ float svals[4];
    __shared__ int   sidx[4];
    const int lane = tid & 63;
    const int wave = tid >> 6;
    if (lane == 0) { svals[wave] = bv; sidx[wave] = bi; }
    __syncthreads();
    if (tid == 0) {
        #pragma unroll
        for (int w = 1; w < 4; ++w) argmax_combine(bv, bi, svals[w], sidx[w]);
        idx_out[t] = bi;
    }
}

__global__ __launch_bounds__(1024) void ctc_compact_kernel(const int* __restrict__ idx,
                                                           int* __restrict__ out) {
    __shared__ int wsum[16];
    const int tid  = threadIdx.x;
    const int base = tid * 4;

    int v[4], keep[4];
    const int prev0 = (base == 0) ? -1 : idx[base - 1];  // sentinel: t=0 always first-of-run
    int cnt = 0;
    #pragma unroll
    for (int k = 0; k < 4; ++k) {
        v[k] = idx[base + k];
        const int p = (k == 0) ? prev0 : v[k - 1];
        keep[k] = (v[k] != p && v[k] != 0) ? 1 : 0;
        cnt += keep[k];
    }

    // inclusive scan of per-thread counts within each 64-lane wave
    const int lane = tid & 63;
    const int wave = tid >> 6;
    int incl = cnt;
    #pragma unroll
    for (int off = 1; off < 64; off <<= 1) {
        int n = __shfl_up(incl, off, 64);
        if (lane >= off) incl += n;
    }
    if (lane == 63) wsum[wave] = incl;

    // fill padded output with -1 (re-poisoned to 0xAA each call, must overwrite)
    #pragma unroll
    for (int k = 0; k < 4; ++k) out[base + k] = -1;
    __syncthreads();

    // scan the 16 wave totals in wave 0
    if (wave == 0) {
        int s = (lane < 16) ? wsum[lane] : 0;
        #pragma unroll
        for (int off = 1; off < 16; off <<= 1) {
            int n = __shfl_up(s, off, 64);
            if (lane >= off) s += n;
        }
        if (lane < 16) wsum[lane] = s;
    }
    __syncthreads();

    const int waveoff = (wave == 0) ? 0 : wsum[wave - 1];
    int pos = waveoff + incl - cnt;  // exclusive prefix for this thread
    #pragma unroll
    for (int k = 0; k < 4; ++k) {
        if (keep[k]) out[pos++] = v[k];
    }
    if (tid == 0) out[T_STEPS] = wsum[15];  // count
}

extern "C" void kernel_launch(void* const* d_in, const int* in_sizes, int n_in,
                              void* d_out, int out_size, void* d_ws, size_t ws_size,
                              hipStream_t stream) {
    const float* em  = (const float*)d_in[0];
    int*         out = (int*)d_out;          // [4097] int32: padded[4096], count
    int*         idx = (int*)d_ws;           // [4096] int32 scratch

    ctc_argmax_kernel<<<dim3(T_STEPS), dim3(256), 0, stream>>>(em, idx);
    ctc_compact_kernel<<<dim3(1), dim3(1024), 0, stream>>>(idx, out);
}

// Round 2
// 659.092 us; speedup vs baseline: 1.0065x; 1.0065x over previous
//
#include <hip/hip_runtime.h>
#include <hip/hip_bf16.h>
#include <math.h>

#define T_STEPS 4096
#define VOCAB   32000
#define NV4     (VOCAB / 4)   // 8000 float4 per row

__device__ __forceinline__ void argmax_combine(float& bv, int& bi, float ov, int oi) {
    // strictly greater wins; on exact tie, smaller index wins (jnp.argmax first-occurrence)
    if (ov > bv || (ov == bv && oi < bi)) { bv = ov; bi = oi; }
}

__device__ __forceinline__ void upd4(float& bv, int& bi, float4 v, int base) {
    if (v.x > bv) { bv = v.x; bi = base + 0; }
    if (v.y > bv) { bv = v.y; bi = base + 1; }
    if (v.z > bv) { bv = v.z; bi = base + 2; }
    if (v.w > bv) { bv = v.w; bi = base + 3; }
}

__global__ __launch_bounds__(256) void ctc_argmax_kernel(const float* __restrict__ em,
                                                         int* __restrict__ idx_out) {
    const int t   = blockIdx.x;
    const int tid = threadIdx.x;
    const float4* row4 = (const float4*)(em + (size_t)t * VOCAB);

    // 4 independent accumulators -> 4 global loads in flight per wave,
    // no serial waitcnt->compare->load chain (latency hiding).
    float bv0 = -INFINITY, bv1 = -INFINITY, bv2 = -INFINITY, bv3 = -INFINITY;
    int   bi0 = 0x7fffffff, bi1 = 0x7fffffff, bi2 = 0x7fffffff, bi3 = 0x7fffffff;

    int j = tid;
    for (; j + 768 < NV4; j += 1024) {
        float4 a = row4[j];
        float4 b = row4[j + 256];
        float4 c = row4[j + 512];
        float4 d = row4[j + 768];
        upd4(bv0, bi0, a, (j)       * 4);
        upd4(bv1, bi1, b, (j + 256) * 4);
        upd4(bv2, bi2, c, (j + 512) * 4);
        upd4(bv3, bi3, d, (j + 768) * 4);
    }
    for (; j < NV4; j += 256) {   // tail (indices ascend within acc0 -> tie-safe)
        float4 a = row4[j];
        upd4(bv0, bi0, a, j * 4);
    }

    argmax_combine(bv0, bi0, bv1, bi1);
    argmax_combine(bv2, bi2, bv3, bi3);
    argmax_combine(bv0, bi0, bv2, bi2);

    // wave (64-lane) butterfly-free down reduction with tie handling
    #pragma unroll
    for (int off = 32; off > 0; off >>= 1) {
        float ov = __shfl_down(bv0, off, 64);
        int   oi = __shfl_down(bi0, off, 64);
        argmax_combine(bv0, bi0, ov, oi);
    }

    __shared__ float svals[4];
    __shared__ int   sidx[4];
    const int lane = tid & 63;
    const int wave = tid >> 6;
    if (lane == 0) { svals[wave] = bv0; sidx[wave] = bi0; }
    __syncthreads();
    if (tid == 0) {
        #pragma unroll
        for (int w = 1; w < 4; ++w) argmax_combine(bv0, bi0, svals[w], sidx[w]);
        idx_out[t] = bi0;
    }
}

__global__ __launch_bounds__(1024) void ctc_compact_kernel(const int* __restrict__ idx,
                                                           int* __restrict__ out) {
    __shared__ int wsum[16];
    const int tid  = threadIdx.x;
    const int base = tid * 4;

    int v[4], keep[4];
    const int prev0 = (base == 0) ? -1 : idx[base - 1];  // sentinel: t=0 always first-of-run
    int cnt = 0;
    #pragma unroll
    for (int k = 0; k < 4; ++k) {
        v[k] = idx[base + k];
        const int p = (k == 0) ? prev0 : v[k - 1];
        keep[k] = (v[k] != p && v[k] != 0) ? 1 : 0;
        cnt += keep[k];
    }

    // inclusive scan of per-thread counts within each 64-lane wave
    const int lane = tid & 63;
    const int wave = tid >> 6;
    int incl = cnt;
    #pragma unroll
    for (int off = 1; off < 64; off <<= 1) {
        int n = __shfl_up(incl, off, 64);
        if (lane >= off) incl += n;
    }
    if (lane == 63) wsum[wave] = incl;

    // fill padded output with -1 (d_out is re-poisoned to 0xAA each call)
    #pragma unroll
    for (int k = 0; k < 4; ++k) out[base + k] = -1;
    __syncthreads();

    // scan the 16 wave totals in wave 0
    if (wave == 0) {
        int s = (lane < 16) ? wsum[lane] : 0;
        #pragma unroll
        for (int off = 1; off < 16; off <<= 1) {
            int n = __shfl_up(s, off, 64);
            if (lane >= off) s += n;
        }
        if (lane < 16) wsum[lane] = s;
    }
    __syncthreads();

    const int waveoff = (wave == 0) ? 0 : wsum[wave - 1];
    int pos = waveoff + incl - cnt;  // exclusive prefix for this thread
    #pragma unroll
    for (int k = 0; k < 4; ++k) {
        if (keep[k]) out[pos++] = v[k];
    }
    if (tid == 0) out[T_STEPS] = wsum[15];  // count
}

extern "C" void kernel_launch(void* const* d_in, const int* in_sizes, int n_in,
                              void* d_out, int out_size, void* d_ws, size_t ws_size,
                              hipStream_t stream) {
    const float* em  = (const float*)d_in[0];
    int*         out = (int*)d_out;          // [4097] int32: padded[4096], count
    int*         idx = (int*)d_ws;           // [4096] int32 scratch

    ctc_argmax_kernel<<<dim3(T_STEPS), dim3(256), 0, stream>>>(em, idx);
    ctc_compact_kernel<<<dim3(1), dim3(1024), 0, stream>>>(idx, out);
}